// Round 11
// baseline (391.495 us; speedup 1.0000x reference)
//
#include <hip/hip_runtime.h>
#include <math.h>

#define B_ 2
#define C_ 192
#define C2_ 384
#define H_ 128
#define W_ 128
#define N_ (H_*W_)      // 16384
#define HEADS_ 4
#define HD_ 48
#define EPS_ 1e-12f

typedef __bf16 bf16x8 __attribute__((ext_vector_type(8)));
typedef __bf16 bf16x4 __attribute__((ext_vector_type(4)));
typedef float  f32x4  __attribute__((ext_vector_type(4)));

// ---------------- K0: pack reg_w -> regwP [ci][t][oc][k] (chunk-major!); kvw -> kvwP [c/32][oc][k];
//                  offw -> offwP [c/32][t][oc32][k] (oc padded 18->32 with zeros), all bf16 ----------------
__global__ __launch_bounds__(256) void k_pack(const float* __restrict__ regw, const float* __restrict__ kvw,
                                              const float* __restrict__ offw,
                                              ushort* __restrict__ regwP, ushort* __restrict__ kvwP,
                                              ushort* __restrict__ offwP) {
    const int NR = 9 * 12 * C2_ * 32;
    const int NK = 6 * C2_ * 32;
    const int NO = 12 * 9 * 32 * 32;
    int idx = blockIdx.x * 256 + threadIdx.x;
    union { __bf16 h; ushort u; } cv;
    if (idx < NR) {
        int ci = idx / (9 * C2_ * 32);
        int r  = idx - ci * (9 * C2_ * 32);
        int t  = r / (C2_ * 32);
        int r2 = r - t * (C2_ * 32);
        int oc = r2 >> 5;
        int kk = r2 & 31;
        cv.h = (__bf16)regw[(oc * C2_ + ci * 32 + kk) * 9 + t];
        regwP[idx] = cv.u;
    } else if (idx < NR + NK) {
        int r  = idx - NR;
        int ci = r / (C2_ * 32);
        int r2 = r - ci * (C2_ * 32);
        int oc = r2 >> 5;
        int kk = r2 & 31;
        cv.h = (__bf16)kvw[oc * C_ + ci * 32 + kk];
        kvwP[r] = cv.u;
    } else if (idx < NR + NK + NO) {
        int r  = idx - NR - NK;
        int ci = r / (9 * 32 * 32);
        int r2 = r - ci * (9 * 32 * 32);
        int t  = r2 / (32 * 32);
        int r3 = r2 - t * (32 * 32);
        int oc = r3 >> 5;
        int kk = r3 & 31;
        float v = (oc < 18) ? offw[(oc * C2_ + ci * 32 + kk) * 9 + t] : 0.f;
        cv.h = (__bf16)v;
        offwP[r] = cv.u;
    }
}

// ---------------- K1: kv 1x1 conv via MFMA -> kvB[b][p][oc] bf16 pixel-major ----------------
__global__ __launch_bounds__(256) void k_kv1x1_mfma(const float* __restrict__ x, const __bf16* __restrict__ kvwP,
                                                    __bf16* __restrict__ kvB) {
    __shared__ __bf16 As[64 * 40];
    __shared__ __bf16 Ws[C2_ * 40];
    const int bid = blockIdx.x;                  // 512 blocks
    const int swz = (bid & 7) * 64 + (bid >> 3); // bijective XCD swizzle
    const int b   = swz >> 8;
    const int p0  = (swz & 255) * 64;
    const int tid  = threadIdx.x;
    const int wv   = tid >> 6;
    const int lane = tid & 63;
    const int fr   = lane & 15;
    const int fg   = lane >> 4;
    const int apx  = tid & 63;    // A-stage: pixel
    const int akg  = tid >> 6;    // A-stage: k-group of 8

    f32x4 acc[4][6];
    #pragma unroll
    for (int mg = 0; mg < 4; ++mg)
        #pragma unroll
        for (int ng = 0; ng < 6; ++ng) acc[mg][ng] = (f32x4){0.f, 0.f, 0.f, 0.f};

    for (int ci = 0; ci < 6; ++ci) {
        const int cc = ci * 32;
        const __bf16* wsrc = kvwP + (size_t)ci * C2_ * 32;
        #pragma unroll
        for (int i = 0; i < 6; ++i) {
            const int e = tid + i * 256;
            const int oc = e >> 2, sg = e & 3;
            *(bf16x8*)&Ws[oc * 40 + sg * 8] = *(const bf16x8*)(wsrc + oc * 32 + sg * 8);
        }
        {
            float v[8];
            #pragma unroll
            for (int j = 0; j < 8; ++j)
                v[j] = x[((size_t)b * C_ + cc + akg * 8 + j) * N_ + p0 + apx];
            bf16x8 pk = {(__bf16)v[0], (__bf16)v[1], (__bf16)v[2], (__bf16)v[3],
                         (__bf16)v[4], (__bf16)v[5], (__bf16)v[6], (__bf16)v[7]};
            *(bf16x8*)&As[apx * 40 + akg * 8] = pk;
        }
        __syncthreads();
        bf16x8 a[4];
        #pragma unroll
        for (int mg = 0; mg < 4; ++mg)
            a[mg] = *(const bf16x8*)&As[(mg * 16 + fr) * 40 + fg * 8];
        #pragma unroll
        for (int ng = 0; ng < 6; ++ng) {
            const bf16x8 bb = *(const bf16x8*)&Ws[(wv * 96 + ng * 16 + fr) * 40 + fg * 8];
            #pragma unroll
            for (int mg = 0; mg < 4; ++mg)
                acc[mg][ng] = __builtin_amdgcn_mfma_f32_16x16x32_bf16(a[mg], bb, acc[mg][ng], 0, 0, 0);
        }
        __syncthreads();
    }
    #pragma unroll
    for (int mg = 0; mg < 4; ++mg)
        #pragma unroll
        for (int j = 0; j < 4; ++j) {
            const int p = p0 + mg * 16 + fg * 4 + j;
            __bf16* dst = kvB + ((size_t)b * N_ + p) * C2_ + wv * 96 + fr;
            #pragma unroll
            for (int ng = 0; ng < 6; ++ng)
                dst[ng * 16] = (__bf16)acc[mg][ng][j];
        }
}

// ---------------- K2: normalize q rows; write f32 qn (output) + bf16 qnB ----------------
__global__ __launch_bounds__(256) void k_qnorm(const float* __restrict__ q, float* __restrict__ qn,
                                               __bf16* __restrict__ qnB) {
    const int row = blockIdx.x;       // b*C + c
    const float* src = q + (size_t)row * N_;
    float* dst = qn + (size_t)row * N_;
    __bf16* dstB = qnB + (size_t)row * N_;
    float ss = 0.f;
    for (int i = threadIdx.x; i < N_ / 4; i += 256) {
        float4 v = ((const float4*)src)[i];
        ss += v.x * v.x + v.y * v.y + v.z * v.z + v.w * v.w;
    }
    __shared__ float red[256];
    red[threadIdx.x] = ss;
    __syncthreads();
    for (int s = 128; s > 0; s >>= 1) {
        if (threadIdx.x < s) red[threadIdx.x] += red[threadIdx.x + s];
        __syncthreads();
    }
    float rn = 1.f / fmaxf(sqrtf(red[0]), EPS_);
    for (int i = threadIdx.x; i < N_ / 8; i += 256) {
        float4 v0 = ((const float4*)src)[2 * i];
        float4 v1 = ((const float4*)src)[2 * i + 1];
        float f0 = v0.x * rn, f1 = v0.y * rn, f2 = v0.z * rn, f3 = v0.w * rn;
        float f4 = v1.x * rn, f5 = v1.y * rn, f6 = v1.z * rn, f7 = v1.w * rn;
        ((float4*)dst)[2 * i]     = make_float4(f0, f1, f2, f3);
        ((float4*)dst)[2 * i + 1] = make_float4(f4, f5, f6, f7);
        bf16x8 pk = {(__bf16)f0, (__bf16)f1, (__bf16)f2, (__bf16)f3,
                     (__bf16)f4, (__bf16)f5, (__bf16)f6, (__bf16)f7};
        *(bf16x8*)&dstB[i * 8] = pk;
    }
}

// ---------------- K3: offset conv3x3 via MFMA: 64-px row strip, LDS kv window ----------------
__global__ __launch_bounds__(256) void k_offconv_mfma(const __bf16* __restrict__ kvB, const __bf16* __restrict__ offwP,
                                                      const float* __restrict__ offb, float* __restrict__ offT) {
    __shared__ __bf16 Win[3 * 66 * 40];   // 3 rows x 66 cols x 32ch (pad 40)
    __shared__ __bf16 Wall[9 * 32 * 40];  // 9 taps x 32 oc x 32 k (pad 40)
    const int bid = blockIdx.x;                  // 512 blocks
    const int swz = (bid & 7) * 64 + (bid >> 3); // bijective XCD swizzle
    const int b   = swz >> 8;
    const int p0  = (swz & 255) * 64;            // 64-px strip within one row
    const int y   = p0 >> 7;
    const int x0  = p0 & 127;
    const int tid  = threadIdx.x;
    const int wv   = tid >> 6;          // wave -> 16-px group
    const int lane = tid & 63;
    const int fr   = lane & 15;
    const int fg   = lane >> 4;
    const __bf16* kb = kvB + (size_t)b * N_ * C2_;

    f32x4 acc[2];
    acc[0] = (f32x4){0.f, 0.f, 0.f, 0.f};
    acc[1] = (f32x4){0.f, 0.f, 0.f, 0.f};

    for (int ci = 0; ci < 12; ++ci) {
        const int cc = ci * 32;
        for (int e = tid; e < 3 * 66 * 4; e += 256) {
            const int r  = e / 264;
            const int rem = e - r * 264;
            const int cw = rem >> 2;
            const int sg = rem & 3;
            const int gy = y - 1 + r;
            const int gx = x0 - 1 + cw;
            bf16x8 v = {};
            if ((unsigned)gy < H_ && (unsigned)gx < W_)
                v = *(const bf16x8*)(kb + ((size_t)(gy * W_ + gx)) * C2_ + cc + sg * 8);
            *(bf16x8*)&Win[(r * 66 + cw) * 40 + sg * 8] = v;
        }
        const __bf16* wsrc = offwP + (size_t)ci * 9 * 32 * 32;
        for (int e = tid; e < 9 * 32 * 4; e += 256) {
            const int t  = e >> 7;
            const int r2 = e & 127;
            const int oc = r2 >> 2;
            const int sg = r2 & 3;
            *(bf16x8*)&Wall[(t * 32 + oc) * 40 + sg * 8] = *(const bf16x8*)(wsrc + (t * 32 + oc) * 32 + sg * 8);
        }
        __syncthreads();
        #pragma unroll
        for (int t = 0; t < 9; ++t) {
            const int dy = t / 3, dx = t % 3;
            const bf16x8 a = *(const bf16x8*)&Win[((dy * 66) + (wv * 16 + fr + dx)) * 40 + fg * 8];
            #pragma unroll
            for (int ng = 0; ng < 2; ++ng) {
                const bf16x8 bb = *(const bf16x8*)&Wall[(t * 32 + ng * 16 + fr) * 40 + fg * 8];
                acc[ng] = __builtin_amdgcn_mfma_f32_16x16x32_bf16(a, bb, acc[ng], 0, 0, 0);
            }
        }
        __syncthreads();
    }
    #pragma unroll
    for (int ng = 0; ng < 2; ++ng) {
        const int oc = ng * 16 + fr;
        if (oc < 18) {
            const float bias = offb[oc];
            #pragma unroll
            for (int j = 0; j < 4; ++j) {
                const int p = p0 + wv * 16 + fg * 4 + j;
                offT[((size_t)b * N_ + p) * 18 + oc] = acc[ng][j] + bias;
            }
        }
    }
}

// ---------------- K4: deformable conv3x3, CHUNK-MAJOR (ci outer, tap inner) for L1 gather reuse ----------------
// 64 px/block, 4 waves (oc-split 96/wave), 54 bodies x 2 K-chunks, ONE barrier/body.
// outputs: kT bf16 [b][oc<192][p] channel-major; vP bf16 [b][p][oc192] pixel-major.

#define ISSUE_GATHER(ITN) do {                                                           \
    _Pragma("unroll")                                                                    \
    for (int h_ = 0; h_ < 2; ++h_) {                                                     \
        const int q_  = 2 * (ITN) + h_;                                                  \
        const int ci_ = q_ / 9;                                                          \
        const int tt_ = q_ - 9 * ci_;                                                    \
        const int4 id4_ = *(const int4*)&sh.m.widx[tt_][spx][0];                         \
        const __bf16* cb_ = kb + ci_ * 32 + ssub;                                        \
        graw[h_][0] = *(const bf16x8*)(cb_ + (size_t)id4_.x * C2_);                      \
        graw[h_][1] = *(const bf16x8*)(cb_ + (size_t)id4_.y * C2_);                      \
        graw[h_][2] = *(const bf16x8*)(cb_ + (size_t)id4_.z * C2_);                      \
        graw[h_][3] = *(const bf16x8*)(cb_ + (size_t)id4_.w * C2_);                      \
    }                                                                                    \
} while (0)

#define PACK_A(ITN, NB) do {                                                             \
    _Pragma("unroll")                                                                    \
    for (int h_ = 0; h_ < 2; ++h_) {                                                     \
        const int q_  = 2 * (ITN) + h_;                                                  \
        const int tt_ = q_ % 9;                                                          \
        const float4 w4_ = *(const float4*)&sh.m.wwt[tt_][spx][0];                       \
        const float wj_[4] = {w4_.x, w4_.y, w4_.z, w4_.w};                               \
        float s_[8] = {0.f,0.f,0.f,0.f,0.f,0.f,0.f,0.f};                                 \
        _Pragma("unroll")                                                                \
        for (int j_ = 0; j_ < 4; ++j_)                                                   \
            _Pragma("unroll")                                                            \
            for (int e_ = 0; e_ < 8; ++e_) s_[e_] += wj_[j_] * (float)graw[h_][j_][e_];  \
        bf16x8 pk_ = {(__bf16)s_[0],(__bf16)s_[1],(__bf16)s_[2],(__bf16)s_[3],           \
                      (__bf16)s_[4],(__bf16)s_[5],(__bf16)s_[6],(__bf16)s_[7]};          \
        *(bf16x8*)&sh.m.As[NB][spx * 72 + h_ * 32 + ssub] = pk_;                         \
    }                                                                                    \
} while (0)

#define DEF_BODY(CUR, NXT) do {                                                          \
    const int ip1_ = (it < 53) ? it + 1 : 53;                                            \
    const int ip2_ = (it < 52) ? it + 2 : 53;                                            \
    bf16x8 bfrB_[6];                                                                     \
    {   const __bf16* wb_ = wbase + (size_t)(2 * it + 1) * (C2_ * 32);                   \
        _Pragma("unroll")                                                                \
        for (int ng_ = 0; ng_ < 6; ++ng_) bfrB_[ng_] = *(const bf16x8*)(wb_ + ng_ * 512); } \
    bf16x8 a0_[4], a1_[4];                                                               \
    _Pragma("unroll")                                                                    \
    for (int mg_ = 0; mg_ < 4; ++mg_) {                                                  \
        a0_[mg_] = *(const bf16x8*)&sh.m.As[CUR][(mg_ * 16 + fr) * 72 + fg * 8];         \
        a1_[mg_] = *(const bf16x8*)&sh.m.As[CUR][(mg_ * 16 + fr) * 72 + 32 + fg * 8];    \
    }                                                                                    \
    PACK_A(ip1_, NXT);                                                                   \
    ISSUE_GATHER(ip2_);                                                                  \
    _Pragma("unroll")                                                                    \
    for (int ng_ = 0; ng_ < 6; ++ng_)                                                    \
        _Pragma("unroll")                                                                \
        for (int mg_ = 0; mg_ < 4; ++mg_)                                                \
            acc[mg_][ng_] = __builtin_amdgcn_mfma_f32_16x16x32_bf16(a0_[mg_], bfrA[ng_], acc[mg_][ng_], 0, 0, 0); \
    _Pragma("unroll")                                                                    \
    for (int ng_ = 0; ng_ < 6; ++ng_)                                                    \
        _Pragma("unroll")                                                                \
        for (int mg_ = 0; mg_ < 4; ++mg_)                                                \
            acc[mg_][ng_] = __builtin_amdgcn_mfma_f32_16x16x32_bf16(a1_[mg_], bfrB_[ng_], acc[mg_][ng_], 0, 0, 0); \
    {   const int nx_ = (it < 53) ? 2 * it + 2 : 107;                                    \
        const __bf16* wb_ = wbase + (size_t)nx_ * (C2_ * 32);                            \
        _Pragma("unroll")                                                                \
        for (int ng_ = 0; ng_ < 6; ++ng_) bfrA[ng_] = *(const bf16x8*)(wb_ + ng_ * 512); } \
    __syncthreads();                                                                     \
    ++it;                                                                                \
} while (0)

__global__ __launch_bounds__(256, 2) void k_deform_mfma(const __bf16* __restrict__ kvB, const float* __restrict__ offT,
                                                        const __bf16* __restrict__ regwP,
                                                        __bf16* __restrict__ kT, __bf16* __restrict__ vP) {
    __shared__ union {
        struct {
            __bf16 As[2][64 * 72];    // double-buffered sampled A tiles (64 px x 64 ch, pad 72)
            float  wwt[9][64][4];     // all taps' bilinear weights
            int    widx[9][64][4];    // all taps' gather indices
        } m;
        __bf16 kTs[192 * 72];         // epilogue k-half transpose buffer
    } sh;
    const int bid = blockIdx.x;                  // 512 blocks
    const int swz = (bid & 7) * 64 + (bid >> 3); // bijective XCD swizzle
    const int b   = swz >> 8;
    const int p0  = (swz & 255) * 64;
    const int tid  = threadIdx.x;
    const int wv   = tid >> 6;          // wave 0..3 -> oc block of 96
    const int lane = tid & 63;
    const int fr   = lane & 15;
    const int fg   = lane >> 4;
    const int spx  = tid >> 2;          // sampling: pixel 0..63
    const int ssub = (tid & 3) * 8;     // sampling: channel sub-offset (8 ch)
    const __bf16* kb    = kvB + (size_t)b * N_ * C2_;
    const __bf16* wbase = regwP + ((size_t)(wv * 96 + fr)) * 32 + fg * 8;

    f32x4 acc[4][6];
    #pragma unroll
    for (int mg = 0; mg < 4; ++mg)
        #pragma unroll
        for (int ng = 0; ng < 6; ++ng) acc[mg][ng] = (f32x4){0.f, 0.f, 0.f, 0.f};

    // ---- precompute bilinear taps for all 9 taps x 64 px ----
    for (int e = tid; e < 576; e += 256) {
        const int tt = e >> 6, pp = e & 63;
        const int p = p0 + pp;
        const int yy = p >> 7, xx = p & 127;
        const float dy = offT[((size_t)b * N_ + p) * 18 + 2 * tt];
        const float dx = offT[((size_t)b * N_ + p) * 18 + 2 * tt + 1];
        const float py = (float)(yy + tt / 3 - 1) + dy;
        const float px = (float)(xx + tt % 3 - 1) + dx;
        const float fy = floorf(py), fx = floorf(px);
        const int y0 = (int)fy, x0i = (int)fx;
        const float ay = py - fy, ax = px - fx;
        #pragma unroll
        for (int j = 0; j < 4; ++j) {
            const int yi = y0 + (j >> 1);
            const int xi = x0i + (j & 1);
            const float wj = ((j >> 1) ? ay : 1.f - ay) * ((j & 1) ? ax : 1.f - ax);
            const bool v = ((unsigned)yi < H_) && ((unsigned)xi < W_);
            sh.m.wwt[tt][pp][j]  = v ? wj : 0.f;
            sh.m.widx[tt][pp][j] = v ? (yi * W_ + xi) : 0;
        }
    }
    __syncthreads();              // taps visible

    bf16x8 graw[2][4];
    bf16x8 bfrA[6];
    ISSUE_GATHER(0);              // graw = data(body 0)
    PACK_A(0, 0);                 // As[0] = A(body 0)
    ISSUE_GATHER(1);              // graw = data(body 1)
    #pragma unroll
    for (int ng = 0; ng < 6; ++ng) bfrA[ng] = *(const bf16x8*)(wbase + ng * 512);  // B(chunk 0)
    __syncthreads();              // As[0] visible

    int it = 0;
    for (int i2 = 0; i2 < 27; ++i2) {
        DEF_BODY(0, 1);
        DEF_BODY(1, 0);
    }

    // ---- epilogue ----
    __syncthreads();   // done with sh.m
    if (wv < 2) {
        // k half: stage transposed into LDS, b64-packed (stride 144B -> light aliasing)
        #pragma unroll
        for (int mg = 0; mg < 4; ++mg)
            #pragma unroll
            for (int ng = 0; ng < 6; ++ng) {
                const int oc = wv * 96 + ng * 16 + fr;
                const bf16x4 pk = {(__bf16)acc[mg][ng][0], (__bf16)acc[mg][ng][1],
                                   (__bf16)acc[mg][ng][2], (__bf16)acc[mg][ng][3]};
                *(bf16x4*)&sh.kTs[oc * 72 + mg * 16 + fg * 4] = pk;
            }
    } else {
        // v half: pixel-major direct (lane-coalesced over oc)
        #pragma unroll
        for (int mg = 0; mg < 4; ++mg)
            #pragma unroll
            for (int j = 0; j < 4; ++j) {
                const int p = p0 + mg * 16 + fg * 4 + j;
                __bf16* dst = vP + ((size_t)b * N_ + p) * C_ + (wv - 2) * 96 + fr;
                #pragma unroll
                for (int ng = 0; ng < 6; ++ng)
                    dst[ng * 16] = (__bf16)acc[mg][ng][j];
            }
    }
    __syncthreads();
    for (int e = tid; e < 192 * 8; e += 256) {
        const int oc = e >> 3, sub = e & 7;
        *(bf16x8*)&kT[((size_t)b * C_ + oc) * N_ + p0 + sub * 8] = *(const bf16x8*)&sh.kTs[oc * 72 + sub * 8];
    }
}

// ---------------- K5: 1/||k row|| from kT bf16 rows ----------------
__global__ __launch_bounds__(256) void k_knorm2(const __bf16* __restrict__ kT, float* __restrict__ knorm) {
    const int row = blockIdx.x;        // b*C + c
    const __bf16* src = kT + (size_t)row * N_;
    float ss = 0.f;
    for (int i = threadIdx.x; i < N_ / 8; i += 256) {
        const bf16x8 v = ((const bf16x8*)src)[i];
        #pragma unroll
        for (int e = 0; e < 8; ++e) { float f = (float)v[e]; ss += f * f; }
    }
    __shared__ float red[256];
    red[threadIdx.x] = ss;
    __syncthreads();
    for (int s = 128; s > 0; s >>= 1) {
        if (threadIdx.x < s) red[threadIdx.x] += red[threadIdx.x + s];
        __syncthreads();
    }
    if (threadIdx.x == 0) knorm[row] = 1.f / fmaxf(sqrtf(red[0]), EPS_);
}

// ---------------- K6a: attention logits via MFMA, 1 wave = 48x48 x K=128 partial ----------------
__global__ __launch_bounds__(256) void k_attn_mfma(const __bf16* __restrict__ qnB, const __bf16* __restrict__ kT,
                                                   float* __restrict__ part) {
    const int bh = blockIdx.y;               // b*HEADS + h
    const int b  = bh >> 2, h = bh & 3;
    const int wv = threadIdx.x >> 6, lane = threadIdx.x & 63;
    const int sl = blockIdx.x * 4 + wv;      // 0..127
    const int n0 = sl * 128;
    const int fr = lane & 15, fg = lane >> 4;
    const __bf16* qb = qnB + ((size_t)b * C_ + h * HD_) * N_ + n0 + fg * 8;
    const __bf16* kb = kT  + ((size_t)b * C_ + h * HD_) * N_ + n0 + fg * 8;
    f32x4 acc[3][3];
    #pragma unroll
    for (int i = 0; i < 3; ++i)
        #pragma unroll
        for (int j = 0; j < 3; ++j) acc[i][j] = (f32x4){0.f, 0.f, 0.f, 0.f};
    #pragma unroll
    for (int kc = 0; kc < 4; ++kc) {
        bf16x8 a[3], bb[3];
        #pragma unroll
        for (int mg = 0; mg < 3; ++mg) a[mg]  = *(const bf16x8*)(qb + (size_t)(mg * 16 + fr) * N_ + kc * 32);
        #pragma unroll
        for (int ng = 0; ng < 3; ++ng) bb[ng] = *(const bf16x8*)(kb + (size_t)(ng * 16 + fr) * N_ + kc * 32);
        #pragma unroll
        for (int mg = 0; mg < 3; ++mg)
            #pragma unroll
            for (int ng = 0; ng < 3; ++ng)
                acc[mg][ng] = __builtin_amdgcn_mfma_f32_16x16x32_bf16(a[mg], bb[ng], acc[mg][ng], 0, 0, 0);
    }
    float* pp = part + ((size_t)bh * 128 + sl) * (HD_ * HD_);
    #pragma unroll
    for (int mg = 0; mg < 3; ++mg)
        #pragma unroll
        for (int ng = 0; ng < 3; ++ng)
            #pragma unroll
            for (int j = 0; j < 4; ++j)
                pp[(mg * 16 + fg * 4 + j) * HD_ + ng * 16 + fr] = acc[mg][ng][j];
}

// ---------------- K6b: reduce 128 partials, scale, softmax over e ----------------
__global__ __launch_bounds__(256) void k_softmax(const float* __restrict__ part, const float* __restrict__ knorm,
                                                 const float* __restrict__ temp, float* __restrict__ attn) {
    const int row = blockIdx.x;    // b*HEADS*HD + h*HD + d
    const int b = row / (HEADS_ * HD_);
    const int r = row % (HEADS_ * HD_);
    const int h = r / HD_;
    const int d = r % HD_;
    const int bh = b * HEADS_ + h;
    const int wv = threadIdx.x >> 6;
    const int lane = threadIdx.x & 63;
    __shared__ float red[4][HD_];
    if (lane < HD_) {
        const float* pp = part + (size_t)bh * 128 * (HD_ * HD_) + d * HD_ + lane;
        float s = 0.f;
        for (int sl = wv; sl < 128; sl += 4)
            s += pp[(size_t)sl * (HD_ * HD_)];
        red[wv][lane] = s;
    }
    __syncthreads();
    if (wv == 0) {
        float v = -INFINITY;
        if (lane < HD_) {
            float t = red[0][lane] + red[1][lane] + red[2][lane] + red[3][lane];
            v = t * knorm[b * C_ + h * HD_ + lane] * temp[h];
        }
        float m = v;
        #pragma unroll
        for (int off = 32; off > 0; off >>= 1) m = fmaxf(m, __shfl_xor(m, off));
        float ex = (lane < HD_) ? expf(v - m) : 0.f;
        float sum = ex;
        #pragma unroll
        for (int off = 32; off > 0; off >>= 1) sum += __shfl_xor(sum, off);
        if (lane < HD_)
            attn[((size_t)bh * HD_ + d) * HD_ + lane] = ex / sum;
    }
}

// ---------------- K7: M[b][oc][h*48+e] = sum_d projw[oc,hd]*attn[bh][d][e] -> bf16 ----------------
__global__ __launch_bounds__(256) void k_m(const float* __restrict__ projw, const float* __restrict__ attn,
                                           __bf16* __restrict__ MmB) {
    const int gid = blockIdx.x * 256 + threadIdx.x;
    if (gid >= B_ * C_ * C_) return;
    const int b  = gid / (C_ * C_);
    const int r  = gid % (C_ * C_);
    const int oc = r / C_;
    const int he = r % C_;
    const int h = he / HD_;
    const int e = he % HD_;
    float s = 0.f;
    #pragma unroll 8
    for (int d = 0; d < HD_; ++d)
        s += projw[oc * C_ + h * HD_ + d] * attn[(((size_t)b * HEADS_ + h) * HD_ + d) * HD_ + e];
    MmB[gid] = (__bf16)s;
}

// ---------------- K8: out[b][oc][p] = sum_he MmB[oc][he] * vP[p][he] via MFMA ----------------
__global__ __launch_bounds__(256) void k_out_mfma(const __bf16* __restrict__ MmB, const __bf16* __restrict__ vP,
                                                  float* __restrict__ out) {
    const int bid = blockIdx.x;                  // 512
    const int swz = (bid & 7) * 64 + (bid >> 3);
    const int b   = swz >> 8;
    const int p0  = (swz & 255) * 64;
    const int wv = threadIdx.x >> 6, lane = threadIdx.x & 63;
    const int fr = lane & 15, fg = lane >> 4;
    const __bf16* vb = vP + ((size_t)b * N_ + p0 + wv * 16 + fr) * C_ + fg * 8;
    const __bf16* mb = MmB + ((size_t)b * C_ + fr) * C_ + fg * 8;
    f32x4 acc[12];
    #pragma unroll
    for (int rr = 0; rr < 12; ++rr) acc[rr] = (f32x4){0.f, 0.f, 0.f, 0.f};
    #pragma unroll
    for (int kc = 0; kc < 6; ++kc) {
        const bf16x8 bb = *(const bf16x8*)(vb + kc * 32);
        #pragma unroll
        for (int rr = 0; rr < 12; ++rr) {
            const bf16x8 a = *(const bf16x8*)(mb + (size_t)(rr * 16) * C_ + kc * 32);
            acc[rr] = __builtin_amdgcn_mfma_f32_16x16x32_bf16(a, bb, acc[rr], 0, 0, 0);
        }
    }
    #pragma unroll
    for (int rr = 0; rr < 12; ++rr)
        #pragma unroll
        for (int j = 0; j < 4; ++j)
            out[((size_t)b * C_ + rr * 16 + fg * 4 + j) * N_ + p0 + wv * 16 + fr] = acc[rr][j];
}

extern "C" void kernel_launch(void* const* d_in, const int* in_sizes, int n_in,
                              void* d_out, int out_size, void* d_ws, size_t ws_size,
                              hipStream_t stream) {
    (void)in_sizes; (void)n_in; (void)out_size; (void)ws_size;
    const float* x     = (const float*)d_in[0];
    const float* q     = (const float*)d_in[1];
    const float* temp  = (const float*)d_in[2];
    const float* kvw   = (const float*)d_in[3];
    const float* offw  = (const float*)d_in[4];
    const float* offb  = (const float*)d_in[5];
    const float* regw  = (const float*)d_in[6];
    const float* projw = (const float*)d_in[7];

    float* out = (float*)d_out;                         // [B][C][N]
    float* qn  = out + (size_t)B_ * C_ * N_;            // [B][C][N] (output 1)
    // kvB (bf16, 25.2 MB) aliases the `out` output region; dead before k_out_mfma writes.
    __bf16* kvB = (__bf16*)out;

    ushort* kT    = (ushort*)d_ws;                          // B*C*N bf16 (k, channel-major)
    ushort* vP    = kT + (size_t)B_ * C_ * N_;              // B*N*C bf16 (v, pixel-major)
    float*  offT  = (float*)(vP + (size_t)B_ * C_ * N_);    // B*N*18 f32
    ushort* regwP = (ushort*)(offT + (size_t)B_ * N_ * 18); // 9*12*384*32 bf16 (chunk-major)
    ushort* kvwP  = regwP + (size_t)9 * 12 * C2_ * 32;      // 6*384*32
    ushort* offwP = kvwP + (size_t)6 * C2_ * 32;            // 12*9*32*32
    ushort* qnB   = offwP + (size_t)12 * 9 * 32 * 32;       // B*C*N bf16
    float*  part  = (float*)(qnB + (size_t)B_ * C_ * N_);   // 8*128*48*48 f32
    float*  attn  = part + (size_t)B_ * HEADS_ * 128 * HD_ * HD_;
    float*  knorm = attn + (size_t)B_ * HEADS_ * HD_ * HD_; // B*C
    ushort* MmB   = (ushort*)(knorm + (size_t)B_ * C_);     // B*C*C bf16

    const int packN = 9 * 12 * C2_ * 32 + 6 * C2_ * 32 + 12 * 9 * 32 * 32;
    k_pack<<<dim3((packN + 255) / 256), 256, 0, stream>>>(regw, kvw, offw, regwP, kvwP, offwP);
    k_kv1x1_mfma<<<dim3(N_ / 64 * B_), 256, 0, stream>>>(x, (const __bf16*)kvwP, kvB);
    k_offconv_mfma<<<dim3(N_ / 64 * B_), 256, 0, stream>>>(kvB, (const __bf16*)offwP, offb, offT);
    k_deform_mfma<<<dim3(N_ / 64 * B_), 256, 0, stream>>>(kvB, offT, (const __bf16*)regwP,
                                                          (__bf16*)kT, (__bf16*)vP);
    // kvB now dead; attention path + outputs
    k_qnorm<<<dim3(B_ * C_), 256, 0, stream>>>(q, qn, (__bf16*)qnB);
    k_knorm2<<<dim3(B_ * C_), 256, 0, stream>>>((const __bf16*)kT, knorm);
    k_attn_mfma<<<dim3(32, B_ * HEADS_), 256, 0, stream>>>((const __bf16*)qnB, (const __bf16*)kT, part);
    k_softmax<<<dim3(B_ * HEADS_ * HD_), 256, 0, stream>>>(part, knorm, temp, attn);
    k_m<<<dim3((B_ * C_ * C_ + 255) / 256), 256, 0, stream>>>(projw, attn, (__bf16*)MmB);
    k_out_mfma<<<dim3(N_ / 64 * B_), 256, 0, stream>>>((const __bf16*)MmB, (const __bf16*)vP, out);
}

// Round 12
// 247.009 us; speedup vs baseline: 1.5849x; 1.5849x over previous
//
#include <hip/hip_runtime.h>
#include <math.h>

#define B_ 2
#define C_ 192
#define C2_ 384
#define H_ 128
#define W_ 128
#define N_ (H_*W_)      // 16384
#define HEADS_ 4
#define HD_ 48
#define EPS_ 1e-12f

typedef __bf16 bf16x8 __attribute__((ext_vector_type(8)));
typedef __bf16 bf16x4 __attribute__((ext_vector_type(4)));
typedef float  f32x4  __attribute__((ext_vector_type(4)));

// ---------------- K0: pack reg_w -> regwP [t][c/32][oc][k] (tap-major); kvw -> kvwP [c/32][oc][k];
//                  offw -> offwP [c/32][t][oc32][k] (oc padded 18->32 with zeros), all bf16 ----------------
__global__ __launch_bounds__(256) void k_pack(const float* __restrict__ regw, const float* __restrict__ kvw,
                                              const float* __restrict__ offw,
                                              ushort* __restrict__ regwP, ushort* __restrict__ kvwP,
                                              ushort* __restrict__ offwP) {
    const int NR = 9 * 12 * C2_ * 32;
    const int NK = 6 * C2_ * 32;
    const int NO = 12 * 9 * 32 * 32;
    int idx = blockIdx.x * 256 + threadIdx.x;
    union { __bf16 h; ushort u; } cv;
    if (idx < NR) {
        int t  = idx / (12 * C2_ * 32);
        int r  = idx - t * (12 * C2_ * 32);
        int ci = r / (C2_ * 32);
        int r2 = r - ci * (C2_ * 32);
        int oc = r2 >> 5;
        int kk = r2 & 31;
        cv.h = (__bf16)regw[(oc * C2_ + ci * 32 + kk) * 9 + t];
        regwP[idx] = cv.u;
    } else if (idx < NR + NK) {
        int r  = idx - NR;
        int ci = r / (C2_ * 32);
        int r2 = r - ci * (C2_ * 32);
        int oc = r2 >> 5;
        int kk = r2 & 31;
        cv.h = (__bf16)kvw[oc * C_ + ci * 32 + kk];
        kvwP[r] = cv.u;
    } else if (idx < NR + NK + NO) {
        int r  = idx - NR - NK;
        int ci = r / (9 * 32 * 32);
        int r2 = r - ci * (9 * 32 * 32);
        int t  = r2 / (32 * 32);
        int r3 = r2 - t * (32 * 32);
        int oc = r3 >> 5;
        int kk = r3 & 31;
        float v = (oc < 18) ? offw[(oc * C2_ + ci * 32 + kk) * 9 + t] : 0.f;
        cv.h = (__bf16)v;
        offwP[r] = cv.u;
    }
}

// ---------------- K1: kv 1x1 conv via MFMA -> kvB[b][p][oc] bf16 pixel-major ----------------
__global__ __launch_bounds__(256) void k_kv1x1_mfma(const float* __restrict__ x, const __bf16* __restrict__ kvwP,
                                                    __bf16* __restrict__ kvB) {
    __shared__ __bf16 As[64 * 40];
    __shared__ __bf16 Ws[C2_ * 40];
    const int bid = blockIdx.x;                  // 512 blocks
    const int swz = (bid & 7) * 64 + (bid >> 3); // bijective XCD swizzle
    const int b   = swz >> 8;
    const int p0  = (swz & 255) * 64;
    const int tid  = threadIdx.x;
    const int wv   = tid >> 6;
    const int lane = tid & 63;
    const int fr   = lane & 15;
    const int fg   = lane >> 4;
    const int apx  = tid & 63;    // A-stage: pixel
    const int akg  = tid >> 6;    // A-stage: k-group of 8

    f32x4 acc[4][6];
    #pragma unroll
    for (int mg = 0; mg < 4; ++mg)
        #pragma unroll
        for (int ng = 0; ng < 6; ++ng) acc[mg][ng] = (f32x4){0.f, 0.f, 0.f, 0.f};

    for (int ci = 0; ci < 6; ++ci) {
        const int cc = ci * 32;
        const __bf16* wsrc = kvwP + (size_t)ci * C2_ * 32;
        #pragma unroll
        for (int i = 0; i < 6; ++i) {
            const int e = tid + i * 256;
            const int oc = e >> 2, sg = e & 3;
            *(bf16x8*)&Ws[oc * 40 + sg * 8] = *(const bf16x8*)(wsrc + oc * 32 + sg * 8);
        }
        {
            float v[8];
            #pragma unroll
            for (int j = 0; j < 8; ++j)
                v[j] = x[((size_t)b * C_ + cc + akg * 8 + j) * N_ + p0 + apx];
            bf16x8 pk = {(__bf16)v[0], (__bf16)v[1], (__bf16)v[2], (__bf16)v[3],
                         (__bf16)v[4], (__bf16)v[5], (__bf16)v[6], (__bf16)v[7]};
            *(bf16x8*)&As[apx * 40 + akg * 8] = pk;
        }
        __syncthreads();
        bf16x8 a[4];
        #pragma unroll
        for (int mg = 0; mg < 4; ++mg)
            a[mg] = *(const bf16x8*)&As[(mg * 16 + fr) * 40 + fg * 8];
        #pragma unroll
        for (int ng = 0; ng < 6; ++ng) {
            const bf16x8 bb = *(const bf16x8*)&Ws[(wv * 96 + ng * 16 + fr) * 40 + fg * 8];
            #pragma unroll
            for (int mg = 0; mg < 4; ++mg)
                acc[mg][ng] = __builtin_amdgcn_mfma_f32_16x16x32_bf16(a[mg], bb, acc[mg][ng], 0, 0, 0);
        }
        __syncthreads();
    }
    #pragma unroll
    for (int mg = 0; mg < 4; ++mg)
        #pragma unroll
        for (int j = 0; j < 4; ++j) {
            const int p = p0 + mg * 16 + fg * 4 + j;
            __bf16* dst = kvB + ((size_t)b * N_ + p) * C2_ + wv * 96 + fr;
            #pragma unroll
            for (int ng = 0; ng < 6; ++ng)
                dst[ng * 16] = (__bf16)acc[mg][ng][j];
        }
}

// ---------------- K2: normalize q rows; write f32 qn (output) + bf16 qnB ----------------
__global__ __launch_bounds__(256) void k_qnorm(const float* __restrict__ q, float* __restrict__ qn,
                                               __bf16* __restrict__ qnB) {
    const int row = blockIdx.x;       // b*C + c
    const float* src = q + (size_t)row * N_;
    float* dst = qn + (size_t)row * N_;
    __bf16* dstB = qnB + (size_t)row * N_;
    float ss = 0.f;
    for (int i = threadIdx.x; i < N_ / 4; i += 256) {
        float4 v = ((const float4*)src)[i];
        ss += v.x * v.x + v.y * v.y + v.z * v.z + v.w * v.w;
    }
    __shared__ float red[256];
    red[threadIdx.x] = ss;
    __syncthreads();
    for (int s = 128; s > 0; s >>= 1) {
        if (threadIdx.x < s) red[threadIdx.x] += red[threadIdx.x + s];
        __syncthreads();
    }
    float rn = 1.f / fmaxf(sqrtf(red[0]), EPS_);
    for (int i = threadIdx.x; i < N_ / 8; i += 256) {
        float4 v0 = ((const float4*)src)[2 * i];
        float4 v1 = ((const float4*)src)[2 * i + 1];
        float f0 = v0.x * rn, f1 = v0.y * rn, f2 = v0.z * rn, f3 = v0.w * rn;
        float f4 = v1.x * rn, f5 = v1.y * rn, f6 = v1.z * rn, f7 = v1.w * rn;
        ((float4*)dst)[2 * i]     = make_float4(f0, f1, f2, f3);
        ((float4*)dst)[2 * i + 1] = make_float4(f4, f5, f6, f7);
        bf16x8 pk = {(__bf16)f0, (__bf16)f1, (__bf16)f2, (__bf16)f3,
                     (__bf16)f4, (__bf16)f5, (__bf16)f6, (__bf16)f7};
        *(bf16x8*)&dstB[i * 8] = pk;
    }
}

// ---------------- K3: offset conv3x3 via MFMA: 64-px row strip, LDS kv window ----------------
__global__ __launch_bounds__(256) void k_offconv_mfma(const __bf16* __restrict__ kvB, const __bf16* __restrict__ offwP,
                                                      const float* __restrict__ offb, float* __restrict__ offT) {
    __shared__ __bf16 Win[3 * 66 * 40];   // 3 rows x 66 cols x 32ch (pad 40)
    __shared__ __bf16 Wall[9 * 32 * 40];  // 9 taps x 32 oc x 32 k (pad 40)
    const int bid = blockIdx.x;                  // 512 blocks
    const int swz = (bid & 7) * 64 + (bid >> 3); // bijective XCD swizzle
    const int b   = swz >> 8;
    const int p0  = (swz & 255) * 64;            // 64-px strip within one row
    const int y   = p0 >> 7;
    const int x0  = p0 & 127;
    const int tid  = threadIdx.x;
    const int wv   = tid >> 6;          // wave -> 16-px group
    const int lane = tid & 63;
    const int fr   = lane & 15;
    const int fg   = lane >> 4;
    const __bf16* kb = kvB + (size_t)b * N_ * C2_;

    f32x4 acc[2];
    acc[0] = (f32x4){0.f, 0.f, 0.f, 0.f};
    acc[1] = (f32x4){0.f, 0.f, 0.f, 0.f};

    for (int ci = 0; ci < 12; ++ci) {
        const int cc = ci * 32;
        for (int e = tid; e < 3 * 66 * 4; e += 256) {
            const int r  = e / 264;
            const int rem = e - r * 264;
            const int cw = rem >> 2;
            const int sg = rem & 3;
            const int gy = y - 1 + r;
            const int gx = x0 - 1 + cw;
            bf16x8 v = {};
            if ((unsigned)gy < H_ && (unsigned)gx < W_)
                v = *(const bf16x8*)(kb + ((size_t)(gy * W_ + gx)) * C2_ + cc + sg * 8);
            *(bf16x8*)&Win[(r * 66 + cw) * 40 + sg * 8] = v;
        }
        const __bf16* wsrc = offwP + (size_t)ci * 9 * 32 * 32;
        for (int e = tid; e < 9 * 32 * 4; e += 256) {
            const int t  = e >> 7;
            const int r2 = e & 127;
            const int oc = r2 >> 2;
            const int sg = r2 & 3;
            *(bf16x8*)&Wall[(t * 32 + oc) * 40 + sg * 8] = *(const bf16x8*)(wsrc + (t * 32 + oc) * 32 + sg * 8);
        }
        __syncthreads();
        #pragma unroll
        for (int t = 0; t < 9; ++t) {
            const int dy = t / 3, dx = t % 3;
            const bf16x8 a = *(const bf16x8*)&Win[((dy * 66) + (wv * 16 + fr + dx)) * 40 + fg * 8];
            #pragma unroll
            for (int ng = 0; ng < 2; ++ng) {
                const bf16x8 bb = *(const bf16x8*)&Wall[(t * 32 + ng * 16 + fr) * 40 + fg * 8];
                acc[ng] = __builtin_amdgcn_mfma_f32_16x16x32_bf16(a, bb, acc[ng], 0, 0, 0);
            }
        }
        __syncthreads();
    }
    #pragma unroll
    for (int ng = 0; ng < 2; ++ng) {
        const int oc = ng * 16 + fr;
        if (oc < 18) {
            const float bias = offb[oc];
            #pragma unroll
            for (int j = 0; j < 4; ++j) {
                const int p = p0 + wv * 16 + fg * 4 + j;
                offT[((size_t)b * N_ + p) * 18 + oc] = acc[ng][j] + bias;
            }
        }
    }
}

// ---------------- K4: deformable conv3x3, CH=64 per barrier (tap-major), gather-prefetch pipeline ----------------
// 64 px/block, 4 waves (oc-split 96/wave), 54 bodies x 2 K-chunks, ONE barrier/body.
// outputs: kT bf16 [b][oc<192][p]; vP bf16 [b][p][oc192]; knp f32 [b][oc<192][pblk] (fused k-norm partials).

#define ISSUE_GATHER(ITN) do {                                                           \
    const int tt_ = (ITN) / 6;                                                           \
    const int ci0_ = 2 * (ITN) - 12 * tt_;                                               \
    const int4 id4_ = *(const int4*)&sh.m.widx[tt_][spx][0];                             \
    const __bf16* cb0_ = kb + ci0_ * 32 + ssub;                                          \
    graw[0][0] = *(const bf16x8*)(cb0_ + (size_t)id4_.x * C2_);                          \
    graw[0][1] = *(const bf16x8*)(cb0_ + (size_t)id4_.y * C2_);                          \
    graw[0][2] = *(const bf16x8*)(cb0_ + (size_t)id4_.z * C2_);                          \
    graw[0][3] = *(const bf16x8*)(cb0_ + (size_t)id4_.w * C2_);                          \
    const __bf16* cb1_ = cb0_ + 32;                                                      \
    graw[1][0] = *(const bf16x8*)(cb1_ + (size_t)id4_.x * C2_);                          \
    graw[1][1] = *(const bf16x8*)(cb1_ + (size_t)id4_.y * C2_);                          \
    graw[1][2] = *(const bf16x8*)(cb1_ + (size_t)id4_.z * C2_);                          \
    graw[1][3] = *(const bf16x8*)(cb1_ + (size_t)id4_.w * C2_);                          \
} while (0)

#define PACK_A(ITN, NB) do {                                                             \
    const int tt_ = (ITN) / 6;                                                           \
    const float4 w4_ = *(const float4*)&sh.m.wwt[tt_][spx][0];                           \
    const float wj_[4] = {w4_.x, w4_.y, w4_.z, w4_.w};                                   \
    _Pragma("unroll")                                                                    \
    for (int h_ = 0; h_ < 2; ++h_) {                                                     \
        float s_[8] = {0.f,0.f,0.f,0.f,0.f,0.f,0.f,0.f};                                 \
        _Pragma("unroll")                                                                \
        for (int j_ = 0; j_ < 4; ++j_)                                                   \
            _Pragma("unroll")                                                            \
            for (int e_ = 0; e_ < 8; ++e_) s_[e_] += wj_[j_] * (float)graw[h_][j_][e_];  \
        bf16x8 pk_ = {(__bf16)s_[0],(__bf16)s_[1],(__bf16)s_[2],(__bf16)s_[3],           \
                      (__bf16)s_[4],(__bf16)s_[5],(__bf16)s_[6],(__bf16)s_[7]};          \
        *(bf16x8*)&sh.m.As[NB][spx * 72 + h_ * 32 + ssub] = pk_;                         \
    }                                                                                    \
} while (0)

#define DEF_BODY(CUR, NXT) do {                                                          \
    const int ip1_ = (it < 53) ? it + 1 : 53;                                            \
    const int ip2_ = (it < 52) ? it + 2 : 53;                                            \
    bf16x8 bfrB_[6];                                                                     \
    {   const __bf16* wb_ = wbase + (size_t)(2 * it + 1) * (C2_ * 32);                   \
        _Pragma("unroll")                                                                \
        for (int ng_ = 0; ng_ < 6; ++ng_) bfrB_[ng_] = *(const bf16x8*)(wb_ + ng_ * 512); } \
    bf16x8 a0_[4], a1_[4];                                                               \
    _Pragma("unroll")                                                                    \
    for (int mg_ = 0; mg_ < 4; ++mg_) {                                                  \
        a0_[mg_] = *(const bf16x8*)&sh.m.As[CUR][(mg_ * 16 + fr) * 72 + fg * 8];         \
        a1_[mg_] = *(const bf16x8*)&sh.m.As[CUR][(mg_ * 16 + fr) * 72 + 32 + fg * 8];    \
    }                                                                                    \
    PACK_A(ip1_, NXT);                                                                   \
    ISSUE_GATHER(ip2_);                                                                  \
    _Pragma("unroll")                                                                    \
    for (int ng_ = 0; ng_ < 6; ++ng_)                                                    \
        _Pragma("unroll")                                                                \
        for (int mg_ = 0; mg_ < 4; ++mg_)                                                \
            acc[mg_][ng_] = __builtin_amdgcn_mfma_f32_16x16x32_bf16(a0_[mg_], bfrA[ng_], acc[mg_][ng_], 0, 0, 0); \
    _Pragma("unroll")                                                                    \
    for (int ng_ = 0; ng_ < 6; ++ng_)                                                    \
        _Pragma("unroll")                                                                \
        for (int mg_ = 0; mg_ < 4; ++mg_)                                                \
            acc[mg_][ng_] = __builtin_amdgcn_mfma_f32_16x16x32_bf16(a1_[mg_], bfrB_[ng_], acc[mg_][ng_], 0, 0, 0); \
    {   const int nx_ = (it < 53) ? 2 * it + 2 : 107;                                    \
        const __bf16* wb_ = wbase + (size_t)nx_ * (C2_ * 32);                            \
        _Pragma("unroll")                                                                \
        for (int ng_ = 0; ng_ < 6; ++ng_) bfrA[ng_] = *(const bf16x8*)(wb_ + ng_ * 512); } \
    __syncthreads();                                                                     \
    ++it;                                                                                \
} while (0)

__global__ __launch_bounds__(256, 2) void k_deform_mfma(const __bf16* __restrict__ kvB, const float* __restrict__ offT,
                                                        const __bf16* __restrict__ regwP,
                                                        __bf16* __restrict__ kT, __bf16* __restrict__ vP,
                                                        float* __restrict__ knp) {
    __shared__ union {
        struct {
            __bf16 As[2][64 * 72];    // double-buffered sampled A tiles (64 px x 64 ch, pad 72)
            float  wwt[9][64][4];     // all taps' bilinear weights
            int    widx[9][64][4];    // all taps' gather indices
        } m;
        __bf16 kTs[192 * 72];         // epilogue k-half transpose buffer
    } sh;
    const int bid = blockIdx.x;                  // 512 blocks
    const int swz = (bid & 7) * 64 + (bid >> 3); // bijective XCD swizzle
    const int b   = swz >> 8;
    const int pblk = swz & 255;
    const int p0  = pblk * 64;
    const int tid  = threadIdx.x;
    const int wv   = tid >> 6;          // wave 0..3 -> oc block of 96
    const int lane = tid & 63;
    const int fr   = lane & 15;
    const int fg   = lane >> 4;
    const int spx  = tid >> 2;          // sampling: pixel 0..63
    const int ssub = (tid & 3) * 8;     // sampling: channel sub-offset (8 ch)
    const __bf16* kb    = kvB + (size_t)b * N_ * C2_;
    const __bf16* wbase = regwP + ((size_t)(wv * 96 + fr)) * 32 + fg * 8;

    f32x4 acc[4][6];
    #pragma unroll
    for (int mg = 0; mg < 4; ++mg)
        #pragma unroll
        for (int ng = 0; ng < 6; ++ng) acc[mg][ng] = (f32x4){0.f, 0.f, 0.f, 0.f};

    // ---- precompute bilinear taps for all 9 taps x 64 px ----
    for (int e = tid; e < 576; e += 256) {
        const int tt = e >> 6, pp = e & 63;
        const int p = p0 + pp;
        const int yy = p >> 7, xx = p & 127;
        const float dy = offT[((size_t)b * N_ + p) * 18 + 2 * tt];
        const float dx = offT[((size_t)b * N_ + p) * 18 + 2 * tt + 1];
        const float py = (float)(yy + tt / 3 - 1) + dy;
        const float px = (float)(xx + tt % 3 - 1) + dx;
        const float fy = floorf(py), fx = floorf(px);
        const int y0 = (int)fy, x0i = (int)fx;
        const float ay = py - fy, ax = px - fx;
        #pragma unroll
        for (int j = 0; j < 4; ++j) {
            const int yi = y0 + (j >> 1);
            const int xi = x0i + (j & 1);
            const float wj = ((j >> 1) ? ay : 1.f - ay) * ((j & 1) ? ax : 1.f - ax);
            const bool v = ((unsigned)yi < H_) && ((unsigned)xi < W_);
            sh.m.wwt[tt][pp][j]  = v ? wj : 0.f;
            sh.m.widx[tt][pp][j] = v ? (yi * W_ + xi) : 0;
        }
    }
    __syncthreads();              // taps visible

    bf16x8 graw[2][4];
    bf16x8 bfrA[6];
    ISSUE_GATHER(0);              // graw = data(body 0)
    PACK_A(0, 0);                 // As[0] = A(body 0)
    ISSUE_GATHER(1);              // graw = data(body 1)
    #pragma unroll
    for (int ng = 0; ng < 6; ++ng) bfrA[ng] = *(const bf16x8*)(wbase + ng * 512);  // B(chunk 0)
    __syncthreads();              // As[0] visible

    int it = 0;
    for (int i2 = 0; i2 < 27; ++i2) {
        DEF_BODY(0, 1);
        DEF_BODY(1, 0);
    }

    // ---- epilogue ----
    __syncthreads();   // done with sh.m
    if (wv < 2) {
        // k half: stage transposed into LDS (b64-packed) + fused per-channel sum-of-squares
        #pragma unroll
        for (int ng = 0; ng < 6; ++ng) {
            const int oc = wv * 96 + ng * 16 + fr;
            float ss = 0.f;
            #pragma unroll
            for (int mg = 0; mg < 4; ++mg) {
                const bf16x4 pk = {(__bf16)acc[mg][ng][0], (__bf16)acc[mg][ng][1],
                                   (__bf16)acc[mg][ng][2], (__bf16)acc[mg][ng][3]};
                *(bf16x4*)&sh.kTs[oc * 72 + mg * 16 + fg * 4] = pk;
                #pragma unroll
                for (int j = 0; j < 4; ++j) ss += acc[mg][ng][j] * acc[mg][ng][j];
            }
            ss += __shfl_xor(ss, 16);
            ss += __shfl_xor(ss, 32);
            if (fg == 0) knp[((size_t)b * C_ + oc) * 256 + pblk] = ss;
        }
    } else {
        // v half: pixel-major direct (lane-coalesced over oc)
        #pragma unroll
        for (int mg = 0; mg < 4; ++mg)
            #pragma unroll
            for (int j = 0; j < 4; ++j) {
                const int p = p0 + mg * 16 + fg * 4 + j;
                __bf16* dst = vP + ((size_t)b * N_ + p) * C_ + (wv - 2) * 96 + fr;
                #pragma unroll
                for (int ng = 0; ng < 6; ++ng)
                    dst[ng * 16] = (__bf16)acc[mg][ng][j];
            }
    }
    __syncthreads();
    for (int e = tid; e < 192 * 8; e += 256) {
        const int oc = e >> 3, sub = e & 7;
        *(bf16x8*)&kT[((size_t)b * C_ + oc) * N_ + p0 + sub * 8] = *(const bf16x8*)&sh.kTs[oc * 72 + sub * 8];
    }
}

// ---------------- K5: reduce knp partials -> knorm[b*C+c] ----------------
__global__ __launch_bounds__(64) void k_knred(const float* __restrict__ knp, float* __restrict__ knorm) {
    const int row = blockIdx.x;        // b*C + c
    const float* src = knp + (size_t)row * 256;
    float s = 0.f;
    for (int i = threadIdx.x; i < 256; i += 64) s += src[i];
    #pragma unroll
    for (int off = 32; off > 0; off >>= 1) s += __shfl_xor(s, off);
    if (threadIdx.x == 0) knorm[row] = 1.f / fmaxf(sqrtf(s), EPS_);
}

// ---------------- K6a: attention logits via MFMA, 1 wave = 48x48 x K=128 partial ----------------
__global__ __launch_bounds__(256) void k_attn_mfma(const __bf16* __restrict__ qnB, const __bf16* __restrict__ kT,
                                                   float* __restrict__ part) {
    const int bh = blockIdx.y;               // b*HEADS + h
    const int b  = bh >> 2, h = bh & 3;
    const int wv = threadIdx.x >> 6, lane = threadIdx.x & 63;
    const int sl = blockIdx.x * 4 + wv;      // 0..127
    const int n0 = sl * 128;
    const int fr = lane & 15, fg = lane >> 4;
    const __bf16* qb = qnB + ((size_t)b * C_ + h * HD_) * N_ + n0 + fg * 8;
    const __bf16* kb = kT  + ((size_t)b * C_ + h * HD_) * N_ + n0 + fg * 8;
    f32x4 acc[3][3];
    #pragma unroll
    for (int i = 0; i < 3; ++i)
        #pragma unroll
        for (int j = 0; j < 3; ++j) acc[i][j] = (f32x4){0.f, 0.f, 0.f, 0.f};
    #pragma unroll
    for (int kc = 0; kc < 4; ++kc) {
        bf16x8 a[3], bb[3];
        #pragma unroll
        for (int mg = 0; mg < 3; ++mg) a[mg]  = *(const bf16x8*)(qb + (size_t)(mg * 16 + fr) * N_ + kc * 32);
        #pragma unroll
        for (int ng = 0; ng < 3; ++ng) bb[ng] = *(const bf16x8*)(kb + (size_t)(ng * 16 + fr) * N_ + kc * 32);
        #pragma unroll
        for (int mg = 0; mg < 3; ++mg)
            #pragma unroll
            for (int ng = 0; ng < 3; ++ng)
                acc[mg][ng] = __builtin_amdgcn_mfma_f32_16x16x32_bf16(a[mg], bb[ng], acc[mg][ng], 0, 0, 0);
    }
    float* pp = part + ((size_t)bh * 128 + sl) * (HD_ * HD_);
    #pragma unroll
    for (int mg = 0; mg < 3; ++mg)
        #pragma unroll
        for (int ng = 0; ng < 3; ++ng)
            #pragma unroll
            for (int j = 0; j < 4; ++j)
                pp[(mg * 16 + fg * 4 + j) * HD_ + ng * 16 + fr] = acc[mg][ng][j];
}

// ---------------- K6b: reduce 128 partials, scale, softmax over e ----------------
__global__ __launch_bounds__(256) void k_softmax(const float* __restrict__ part, const float* __restrict__ knorm,
                                                 const float* __restrict__ temp, float* __restrict__ attn) {
    const int row = blockIdx.x;    // b*HEADS*HD + h*HD + d
    const int b = row / (HEADS_ * HD_);
    const int r = row % (HEADS_ * HD_);
    const int h = r / HD_;
    const int d = r % HD_;
    const int bh = b * HEADS_ + h;
    const int wv = threadIdx.x >> 6;
    const int lane = threadIdx.x & 63;
    __shared__ float red[4][HD_];
    if (lane < HD_) {
        const float* pp = part + (size_t)bh * 128 * (HD_ * HD_) + d * HD_ + lane;
        float s = 0.f;
        for (int sl = wv; sl < 128; sl += 4)
            s += pp[(size_t)sl * (HD_ * HD_)];
        red[wv][lane] = s;
    }
    __syncthreads();
    if (wv == 0) {
        float v = -INFINITY;
        if (lane < HD_) {
            float t = red[0][lane] + red[1][lane] + red[2][lane] + red[3][lane];
            v = t * knorm[b * C_ + h * HD_ + lane] * temp[h];
        }
        float m = v;
        #pragma unroll
        for (int off = 32; off > 0; off >>= 1) m = fmaxf(m, __shfl_xor(m, off));
        float ex = (lane < HD_) ? expf(v - m) : 0.f;
        float sum = ex;
        #pragma unroll
        for (int off = 32; off > 0; off >>= 1) sum += __shfl_xor(sum, off);
        if (lane < HD_)
            attn[((size_t)bh * HD_ + d) * HD_ + lane] = ex / sum;
    }
}

// ---------------- K7: M[b][oc][h*48+e] = sum_d projw[oc,hd]*attn[bh][d][e] -> bf16 ----------------
__global__ __launch_bounds__(256) void k_m(const float* __restrict__ projw, const float* __restrict__ attn,
                                           __bf16* __restrict__ MmB) {
    const int gid = blockIdx.x * 256 + threadIdx.x;
    if (gid >= B_ * C_ * C_) return;
    const int b  = gid / (C_ * C_);
    const int r  = gid % (C_ * C_);
    const int oc = r / C_;
    const int he = r % C_;
    const int h = he / HD_;
    const int e = he % HD_;
    float s = 0.f;
    #pragma unroll 8
    for (int d = 0; d < HD_; ++d)
        s += projw[oc * C_ + h * HD_ + d] * attn[(((size_t)b * HEADS_ + h) * HD_ + d) * HD_ + e];
    MmB[gid] = (__bf16)s;
}

// ---------------- K8: out[b][oc][p] = sum_he MmB[oc][he] * vP[p][he] via MFMA ----------------
__global__ __launch_bounds__(256) void k_out_mfma(const __bf16* __restrict__ MmB, const __bf16* __restrict__ vP,
                                                  float* __restrict__ out) {
    const int bid = blockIdx.x;                  // 512
    const int swz = (bid & 7) * 64 + (bid >> 3);
    const int b   = swz >> 8;
    const int p0  = (swz & 255) * 64;
    const int wv = threadIdx.x >> 6, lane = threadIdx.x & 63;
    const int fr = lane & 15, fg = lane >> 4;
    const __bf16* vb = vP + ((size_t)b * N_ + p0 + wv * 16 + fr) * C_ + fg * 8;
    const __bf16* mb = MmB + ((size_t)b * C_ + fr) * C_ + fg * 8;
    f32x4 acc[12];
    #pragma unroll
    for (int rr = 0; rr < 12; ++rr) acc[rr] = (f32x4){0.f, 0.f, 0.f, 0.f};
    #pragma unroll
    for (int kc = 0; kc < 6; ++kc) {
        const bf16x8 bb = *(const bf16x8*)(vb + kc * 32);
        #pragma unroll
        for (int rr = 0; rr < 12; ++rr) {
            const bf16x8 a = *(const bf16x8*)(mb + (size_t)(rr * 16) * C_ + kc * 32);
            acc[rr] = __builtin_amdgcn_mfma_f32_16x16x32_bf16(a, bb, acc[rr], 0, 0, 0);
        }
    }
    #pragma unroll
    for (int rr = 0; rr < 12; ++rr)
        #pragma unroll
        for (int j = 0; j < 4; ++j)
            out[((size_t)b * C_ + rr * 16 + fg * 4 + j) * N_ + p0 + wv * 16 + fr] = acc[rr][j];
}

extern "C" void kernel_launch(void* const* d_in, const int* in_sizes, int n_in,
                              void* d_out, int out_size, void* d_ws, size_t ws_size,
                              hipStream_t stream) {
    (void)in_sizes; (void)n_in; (void)out_size; (void)ws_size;
    const float* x     = (const float*)d_in[0];
    const float* q     = (const float*)d_in[1];
    const float* temp  = (const float*)d_in[2];
    const float* kvw   = (const float*)d_in[3];
    const float* offw  = (const float*)d_in[4];
    const float* offb  = (const float*)d_in[5];
    const float* regw  = (const float*)d_in[6];
    const float* projw = (const float*)d_in[7];

    float* out = (float*)d_out;                         // [B][C][N]
    float* qn  = out + (size_t)B_ * C_ * N_;            // [B][C][N] (output 1)
    // kvB (bf16, 25.2 MB) aliases the `out` output region; dead before k_out_mfma writes.
    __bf16* kvB = (__bf16*)out;

    ushort* kT    = (ushort*)d_ws;                          // B*C*N bf16 (k, channel-major)
    ushort* vP    = kT + (size_t)B_ * C_ * N_;              // B*N*C bf16 (v, pixel-major)
    float*  offT  = (float*)(vP + (size_t)B_ * C_ * N_);    // B*N*18 f32
    ushort* regwP = (ushort*)(offT + (size_t)B_ * N_ * 18); // 9*12*384*32 bf16 (tap-major)
    ushort* kvwP  = regwP + (size_t)9 * 12 * C2_ * 32;      // 6*384*32
    ushort* offwP = kvwP + (size_t)6 * C2_ * 32;            // 12*9*32*32
    ushort* qnB   = offwP + (size_t)12 * 9 * 32 * 32;       // B*C*N bf16
    float*  part  = (float*)(qnB + (size_t)B_ * C_ * N_);   // 8*128*48*48 f32
    float*  attn  = part + (size_t)B_ * HEADS_ * 128 * HD_ * HD_;
    float*  knorm = attn + (size_t)B_ * HEADS_ * HD_ * HD_; // B*C
    ushort* MmB   = (ushort*)(knorm + (size_t)B_ * C_);     // B*C*C bf16
    float*  knp   = (float*)(MmB + (size_t)B_ * C_ * C_);   // B*C*256 f32 (k-norm partials)

    const int packN = 9 * 12 * C2_ * 32 + 6 * C2_ * 32 + 12 * 9 * 32 * 32;
    k_pack<<<dim3((packN + 255) / 256), 256, 0, stream>>>(regw, kvw, offw, regwP, kvwP, offwP);
    k_kv1x1_mfma<<<dim3(N_ / 64 * B_), 256, 0, stream>>>(x, (const __bf16*)kvwP, kvB);
    k_offconv_mfma<<<dim3(N_ / 64 * B_), 256, 0, stream>>>(kvB, (const __bf16*)offwP, offb, offT);
    k_deform_mfma<<<dim3(N_ / 64 * B_), 256, 0, stream>>>(kvB, offT, (const __bf16*)regwP,
                                                          (__bf16*)kT, (__bf16*)vP, knp);
    // kvB now dead; attention path + outputs
    k_qnorm<<<dim3(B_ * C_), 256, 0, stream>>>(q, qn, (__bf16*)qnB);
    k_knred<<<dim3(B_ * C_), 64, 0, stream>>>(knp, knorm);
    k_attn_mfma<<<dim3(32, B_ * HEADS_), 256, 0, stream>>>((const __bf16*)qnB, (const __bf16*)kT, part);
    k_softmax<<<dim3(B_ * HEADS_ * HD_), 256, 0, stream>>>(part, knorm, temp, attn);
    k_m<<<dim3((B_ * C_ * C_ + 255) / 256), 256, 0, stream>>>(projw, attn, (__bf16*)MmB);
    k_out_mfma<<<dim3(N_ / 64 * B_), 256, 0, stream>>>((const __bf16*)MmB, (const __bf16*)vP, out);
}